// Round 1
// baseline (48.790 us; speedup 1.0000x reference)
//
#include <hip/hip_runtime.h>

#define B_ 64
#define T_ 512
#define D_ 1024
#define K_ 10
constexpr float TEMP_ = 0.07f;
constexpr float EPS_ = 1e-8f;
constexpr int CHUNK = 32;           // anchors per block
constexpr int NCHUNK = 16;          // ceil(510/32)
constexpr int F4ROW = D_ / 4;       // 256 float4 per row

__device__ __forceinline__ float dot4(float4 a, float4 b) {
    return a.x * b.x + a.y * b.y + a.z * b.z + a.w * b.w;
}

// ---- 16-lane reduction via DPP row_ror (pure VALU pipe) ----
#if __has_builtin(__builtin_amdgcn_update_dpp)
template <int CTRL>
__device__ __forceinline__ float dpp_add(float x) {
    int y = __builtin_amdgcn_update_dpp(0, __float_as_int(x), CTRL, 0xf, 0xf, false);
    return x + __int_as_float(y);
}
__device__ __forceinline__ float red16(float x) {
    x = dpp_add<0x128>(x);  // row_ror:8
    x = dpp_add<0x124>(x);  // row_ror:4
    x = dpp_add<0x122>(x);  // row_ror:2
    x = dpp_add<0x121>(x);  // row_ror:1
    return x;               // all 16 lanes hold the group sum
}
#else
__device__ __forceinline__ float red16(float x) {
    x += __shfl_xor(x, 8, 16);
    x += __shfl_xor(x, 4, 16);
    x += __shfl_xor(x, 2, 16);
    x += __shfl_xor(x, 1, 16);
    return x;
}
#endif

__global__ __launch_bounds__(256) void signcl_main(
    const float* __restrict__ features,
    const int* __restrict__ neg_b,
    const int* __restrict__ neg_t,
    float* __restrict__ partials)
{
    __shared__ float s_negs[K_ * D_];   // 40960 B, unit-normalized negatives
    __shared__ float s_inv[K_];
    __shared__ float s_part[16];

    const int bid = blockIdx.x;
    const int b = bid >> 4;             // / NCHUNK
    const int c = bid & (NCHUNK - 1);
    const int tid = threadIdx.x;

    const float4* f4 = reinterpret_cast<const float4*>(features);
    float4* s4 = reinterpret_cast<float4*>(s_negs);

    // ---- stage negatives to LDS (2560 float4 over 256 threads) ----
#pragma unroll
    for (int it = 0; it < 10; ++it) {
        int idx = tid + it * 256;       // 0..2559
        int k = idx >> 8;               // idx / 256
        int off = idx & 255;
        int nb = neg_b[b * K_ + k];
        int nt = neg_t[b * K_ + k];
        s4[idx] = f4[((size_t)nb * T_ + nt) * F4ROW + off];
    }
    __syncthreads();

    // ---- per-negative inverse norms (wave w handles k = w, w+4, w+8) ----
    const int lane = tid & 63;
    const int w = tid >> 6;
    for (int k = w; k < K_; k += 4) {
        float ss = 0.f;
#pragma unroll
        for (int s = 0; s < 4; ++s) {
            float4 v = s4[k * F4ROW + s * 64 + lane];
            ss += dot4(v, v);
        }
#pragma unroll
        for (int m = 32; m >= 1; m >>= 1) ss += __shfl_xor(ss, m, 64);
        if (lane == 0) s_inv[k] = 1.f / fmaxf(sqrtf(ss), EPS_);
    }
    __syncthreads();

    // ---- normalize negatives in place ----
#pragma unroll
    for (int it = 0; it < 10; ++it) {
        int idx = tid + it * 256;
        float inv = s_inv[idx >> 8];
        float4 v = s4[idx];
        v.x *= inv; v.y *= inv; v.z *= inv; v.w *= inv;
        s4[idx] = v;
    }
    __syncthreads();

    // ---- main: anchors [t0, t1); 16 lanes per anchor-pair ----
    const int t0 = 1 + c * CHUNK;
    const int t1 = min(t0 + CHUNK, T_ - 1);   // anchors are t=1..510
    const int g = lane >> 4;                  // group 0..3
    const int i = lane & 15;                  // lane within group
    const int ta = t0 + w * 8 + 2 * g;        // first anchor of this pair

    const size_t rowbase = (size_t)b * T_ * F4ROW;
    const float4* p0 = f4 + rowbase + (size_t)min(ta,     T_ - 1) * F4ROW;
    const float4* p1 = f4 + rowbase + (size_t)min(ta + 1, T_ - 1) * F4ROW;
    const float4* p2 = f4 + rowbase + (size_t)min(ta + 2, T_ - 1) * F4ROW;

    float ss0 = 0.f, ss1 = 0.f, ss2 = 0.f, dp01 = 0.f, dp12 = 0.f;
    float nd0[K_], nd1[K_];
#pragma unroll
    for (int k = 0; k < K_; ++k) { nd0[k] = 0.f; nd1[k] = 0.f; }

#pragma unroll 4
    for (int s = 0; s < 16; ++s) {
        int fi = s * 16 + i;                  // lane's float4 index in the row
        float4 a = p0[fi];
        float4 p = p1[fi];
        float4 q = p2[fi];
        ss0  += dot4(a, a);
        ss1  += dot4(p, p);
        ss2  += dot4(q, q);
        dp01 += dot4(a, p);
        dp12 += dot4(p, q);
#pragma unroll
        for (int k = 0; k < K_; ++k) {
            float4 n = s4[k * F4ROW + fi];    // same addr across groups -> broadcast
            nd0[k] += dot4(a, n);
            nd1[k] += dot4(p, n);
        }
    }

    // ---- reduce the 25 partial sums within each 16-lane group ----
    ss0 = red16(ss0); ss1 = red16(ss1); ss2 = red16(ss2);
    dp01 = red16(dp01); dp12 = red16(dp12);
#pragma unroll
    for (int k = 0; k < K_; ++k) { nd0[k] = red16(nd0[k]); nd1[k] = red16(nd1[k]); }

    const float invT = 1.f / TEMP_;
    const float inv0 = 1.f / fmaxf(sqrtf(ss0), EPS_);
    const float inv1 = 1.f / fmaxf(sqrtf(ss1), EPS_);
    const float inv2 = 1.f / fmaxf(sqrtf(ss2), EPS_);

    float lsum = 0.f;
    if (ta < t1) {
        float pos = dp01 * inv0 * inv1 * invT;
        float se = 0.f;
#pragma unroll
        for (int k = 0; k < K_; ++k) se += __expf(nd0[k] * inv0 * invT);
        lsum += __logf(__expf(pos) + se) - pos;
    }
    if (ta + 1 < t1) {
        float pos = dp12 * inv1 * inv2 * invT;
        float se = 0.f;
#pragma unroll
        for (int k = 0; k < K_; ++k) se += __expf(nd1[k] * inv1 * invT);
        lsum += __logf(__expf(pos) + se) - pos;
    }

    if (i == 0) s_part[w * 4 + g] = lsum;     // 16 group leaders, distinct slots
    __syncthreads();
    if (tid == 0) {
        float t = 0.f;
#pragma unroll
        for (int j = 0; j < 16; ++j) t += s_part[j];
        partials[bid] = t;
    }
}

__global__ __launch_bounds__(256) void signcl_reduce(
    const float* __restrict__ partials, float* __restrict__ out)
{
    __shared__ float s_w[4];
    const int tid = threadIdx.x;
    float s = 0.f;
    for (int idx = tid; idx < B_ * NCHUNK; idx += 256) s += partials[idx];
#pragma unroll
    for (int m = 32; m >= 1; m >>= 1) s += __shfl_xor(s, m, 64);
    const int w = tid >> 6, lane = tid & 63;
    if (lane == 0) s_w[w] = s;
    __syncthreads();
    if (tid == 0) {
        float t = s_w[0] + s_w[1] + s_w[2] + s_w[3];
        out[0] = t / (float)(B_ * (T_ - 2));
    }
}

extern "C" void kernel_launch(void* const* d_in, const int* in_sizes, int n_in,
                              void* d_out, int out_size, void* d_ws, size_t ws_size,
                              hipStream_t stream) {
    const float* features = (const float*)d_in[0];
    const int* neg_b = (const int*)d_in[1];
    const int* neg_t = (const int*)d_in[2];
    float* partials = (float*)d_ws;          // 1024 floats, fully overwritten each call

    signcl_main<<<B_ * NCHUNK, 256, 0, stream>>>(features, neg_b, neg_t, partials);
    signcl_reduce<<<1, 256, 0, stream>>>(partials, (float*)d_out);
}

// Round 2
// 46.353 us; speedup vs baseline: 1.0526x; 1.0526x over previous
//
#include <hip/hip_runtime.h>

#define B_ 64
#define T_ 512
#define D_ 1024
#define K_ 10
constexpr float TEMP_ = 0.07f;
constexpr float EPS_ = 1e-8f;
constexpr int CHUNK = 16;           // anchors per block
constexpr int NCHUNK = 32;          // 512 slots for 510 anchors
constexpr int F4ROW = D_ / 4;       // 256 float4 per row

__device__ __forceinline__ float dot4(float4 a, float4 b) {
    return a.x * b.x + a.y * b.y + a.z * b.z + a.w * b.w;
}

// bf16 round-to-nearest-even pack/unpack (pair in one u32: lo = elem 2p, hi = elem 2p+1)
__device__ __forceinline__ unsigned bfr_(float f) {
    unsigned u = __float_as_uint(f);
    return (u + 0x7fffu + ((u >> 16) & 1u)) >> 16;
}
__device__ __forceinline__ unsigned pack2_(float lo, float hi) {
    return bfr_(lo) | (bfr_(hi) << 16);
}
__device__ __forceinline__ float plo_(unsigned u) { return __uint_as_float(u << 16); }
__device__ __forceinline__ float phi_(unsigned u) { return __uint_as_float(u & 0xffff0000u); }

// ---- reductions on the VALU (DPP row_ror within 16) + ds_swizzle for the 16-cross ----
template <int CTRL>
__device__ __forceinline__ float dpp_add(float x) {
    int y = __builtin_amdgcn_update_dpp(0, __float_as_int(x), CTRL, 0xf, 0xf, false);
    return x + __int_as_float(y);
}
__device__ __forceinline__ float red32(float x) {
    x = dpp_add<0x128>(x);  // row_ror:8
    x = dpp_add<0x124>(x);  // row_ror:4
    x = dpp_add<0x122>(x);  // row_ror:2
    x = dpp_add<0x121>(x);  // row_ror:1  -> 16-lane sums
    int y = __builtin_amdgcn_ds_swizzle(__float_as_int(x), 0x401F); // xor lane^16
    return x + __int_as_float(y);
}

__global__ __launch_bounds__(256, 7) void signcl_main(
    const float* __restrict__ features,
    const int* __restrict__ neg_b,
    const int* __restrict__ neg_t,
    float* __restrict__ partials)
{
    __shared__ unsigned s_negs[K_ * 512];   // 20480 B: bf16-pair-packed unit negatives
    __shared__ float s_inv[K_];
    __shared__ float s_part[8];

    const int bid = blockIdx.x;
    const int b = bid >> 5;                 // / NCHUNK
    const int c = bid & (NCHUNK - 1);
    const int tid = threadIdx.x;

    const float4* f4 = reinterpret_cast<const float4*>(features);

    // ---- Phase A: gather negatives, pack to bf16 pairs in LDS ----
    uint2* s2 = reinterpret_cast<uint2*>(s_negs);
#pragma unroll
    for (int it = 0; it < 10; ++it) {
        int idx = tid + it * 256;           // 0..2559 float4s
        int k = idx >> 8;
        int off = idx & 255;
        int nb = neg_b[b * K_ + k];
        int nt = neg_t[b * K_ + k];
        float4 v = f4[((size_t)nb * T_ + nt) * F4ROW + off];
        uint2 p;
        p.x = pack2_(v.x, v.y);
        p.y = pack2_(v.z, v.w);
        s2[idx] = p;
    }
    __syncthreads();

    // ---- Phase B: per-negative inverse norms ----
    const int lane = tid & 63;
    const int w = tid >> 6;
    for (int k = w; k < K_; k += 4) {
        const uint4* r4 = reinterpret_cast<const uint4*>(s_negs + k * 512);
        float ss = 0.f;
#pragma unroll
        for (int j = 0; j < 2; ++j) {
            uint4 u = r4[j * 64 + lane];
            float e0 = plo_(u.x), e1 = phi_(u.x), e2 = plo_(u.y), e3 = phi_(u.y);
            float e4 = plo_(u.z), e5 = phi_(u.z), e6 = plo_(u.w), e7 = phi_(u.w);
            ss += e0*e0 + e1*e1 + e2*e2 + e3*e3 + e4*e4 + e5*e5 + e6*e6 + e7*e7;
        }
#pragma unroll
        for (int m = 32; m >= 1; m >>= 1) ss += __shfl_xor(ss, m, 64);
        if (lane == 0) s_inv[k] = 1.f / fmaxf(sqrtf(ss), EPS_);
    }
    __syncthreads();

    // ---- Phase C: normalize in place (repack) ----
    uint4* s4u = reinterpret_cast<uint4*>(s_negs);
#pragma unroll
    for (int j = 0; j < 5; ++j) {
        int idx4 = tid + j * 256;           // 0..1279 uint4s (128 per neg row)
        float inv = s_inv[idx4 >> 7];
        uint4 u = s4u[idx4];
        u.x = pack2_(plo_(u.x) * inv, phi_(u.x) * inv);
        u.y = pack2_(plo_(u.y) * inv, phi_(u.y) * inv);
        u.z = pack2_(plo_(u.z) * inv, phi_(u.z) * inv);
        u.w = pack2_(plo_(u.w) * inv, phi_(u.w) * inv);
        s4u[idx4] = u;
    }
    __syncthreads();

    // ---- Phase D: 8 groups of 32 lanes, one anchor-pair per group ----
    const int gid = tid >> 5;               // 0..7
    const int i = tid & 31;
    const int t0 = 1 + c * CHUNK;
    const int t1 = min(t0 + CHUNK, T_ - 1); // anchors are t = 1..510
    const int ta = t0 + gid * 2;

    const size_t rowbase = (size_t)b * T_ * F4ROW;
    const float4* p0 = f4 + rowbase + (size_t)min(ta,     T_ - 1) * F4ROW;
    const float4* p1 = f4 + rowbase + (size_t)min(ta + 1, T_ - 1) * F4ROW;
    const float4* p2 = f4 + rowbase + (size_t)min(ta + 2, T_ - 1) * F4ROW;

    float ss0 = 0.f, ss1 = 0.f, ss2 = 0.f, dp01 = 0.f, dp12 = 0.f;
    float nd0[K_], nd1[K_];
#pragma unroll
    for (int k = 0; k < K_; ++k) { nd0[k] = 0.f; nd1[k] = 0.f; }

#pragma unroll
    for (int s = 0; s < 4; ++s) {
        int fi4 = s * 64 + i * 2;           // lane's 8 contiguous f32 = 2 float4
        float4 a0 = p0[fi4], a1 = p0[fi4 + 1];
        float4 b0 = p1[fi4], b1 = p1[fi4 + 1];
        float4 q0 = p2[fi4], q1 = p2[fi4 + 1];
        ss0  += dot4(a0, a0) + dot4(a1, a1);
        ss1  += dot4(b0, b0) + dot4(b1, b1);
        ss2  += dot4(q0, q0) + dot4(q1, q1);
        dp01 += dot4(a0, b0) + dot4(a1, b1);
        dp12 += dot4(b0, q0) + dot4(b1, q1);
        const uint4* nrow = reinterpret_cast<const uint4*>(s_negs) + s * 32 + i;
#pragma unroll
        for (int k = 0; k < K_; ++k) {
            uint4 u = nrow[k * 128];        // same addr for both wave halves -> broadcast
            float n0 = plo_(u.x), n1 = phi_(u.x), n2 = plo_(u.y), n3 = phi_(u.y);
            float n4 = plo_(u.z), n5 = phi_(u.z), n6 = plo_(u.w), n7 = phi_(u.w);
            nd0[k] += a0.x*n0 + a0.y*n1 + a0.z*n2 + a0.w*n3
                    + a1.x*n4 + a1.y*n5 + a1.z*n6 + a1.w*n7;
            nd1[k] += b0.x*n0 + b0.y*n1 + b0.z*n2 + b0.w*n3
                    + b1.x*n4 + b1.y*n5 + b1.z*n6 + b1.w*n7;
        }
    }

    // ---- reduce 25 partials within each 32-lane group ----
    ss0 = red32(ss0); ss1 = red32(ss1); ss2 = red32(ss2);
    dp01 = red32(dp01); dp12 = red32(dp12);
#pragma unroll
    for (int k = 0; k < K_; ++k) { nd0[k] = red32(nd0[k]); nd1[k] = red32(nd1[k]); }

    const float invT = 1.f / TEMP_;
    const float inv0 = 1.f / fmaxf(sqrtf(ss0), EPS_);
    const float inv1 = 1.f / fmaxf(sqrtf(ss1), EPS_);
    const float inv2 = 1.f / fmaxf(sqrtf(ss2), EPS_);

    float lsum = 0.f;
    if (ta < t1) {
        float pos = dp01 * inv0 * inv1 * invT;
        float se = 0.f;
#pragma unroll
        for (int k = 0; k < K_; ++k) se += __expf(nd0[k] * inv0 * invT);
        lsum += __logf(__expf(pos) + se) - pos;
    }
    if (ta + 1 < t1) {
        float pos = dp12 * inv1 * inv2 * invT;
        float se = 0.f;
#pragma unroll
        for (int k = 0; k < K_; ++k) se += __expf(nd1[k] * inv1 * invT);
        lsum += __logf(__expf(pos) + se) - pos;
    }

    if (i == 0) s_part[gid] = lsum;
    __syncthreads();
    if (tid == 0) {
        float t = 0.f;
#pragma unroll
        for (int j = 0; j < 8; ++j) t += s_part[j];
        partials[bid] = t;
    }
}

__global__ __launch_bounds__(256) void signcl_reduce(
    const float* __restrict__ partials, float* __restrict__ out)
{
    __shared__ float s_w[4];
    const int tid = threadIdx.x;
    float s = 0.f;
    for (int idx = tid; idx < B_ * NCHUNK; idx += 256) s += partials[idx];
#pragma unroll
    for (int m = 32; m >= 1; m >>= 1) s += __shfl_xor(s, m, 64);
    const int w = tid >> 6, lane = tid & 63;
    if (lane == 0) s_w[w] = s;
    __syncthreads();
    if (tid == 0) {
        float t = s_w[0] + s_w[1] + s_w[2] + s_w[3];
        out[0] = t / (float)(B_ * (T_ - 2));
    }
}

extern "C" void kernel_launch(void* const* d_in, const int* in_sizes, int n_in,
                              void* d_out, int out_size, void* d_ws, size_t ws_size,
                              hipStream_t stream) {
    const float* features = (const float*)d_in[0];
    const int* neg_b = (const int*)d_in[1];
    const int* neg_t = (const int*)d_in[2];
    float* partials = (float*)d_ws;          // 2048 floats, fully overwritten each call

    signcl_main<<<B_ * NCHUNK, 256, 0, stream>>>(features, neg_b, neg_t, partials);
    signcl_reduce<<<1, 256, 0, stream>>>(partials, (float*)d_out);
}